// Round 16
// baseline (89.082 us; speedup 1.0000x reference)
//
#include <hip/hip_runtime.h>
#include <stdint.h>

#define T 16
#define NB 8
#define NROI 20000
#define NA 5
#define MM (NROI + NA)   // 20005
#define MMPAD 20224      // per-(img,a) ov stride
#define RPI 128
#define FGPI 32
#define NBLK 79          // blocks per image in k_iou
#define NBLK2 20         // 1024-thread blocks per image in k_fused
#define SORTCAP 32768
#define LCAP 16384       // LDS bucket capacity (128 KiB)
#define NBUCK 2048

// ---------------- threefry2x32 (JAX-exact, 20 rounds), host+device ----------------
__host__ __device__ __forceinline__ void tf2x32(uint32_t k0, uint32_t k1,
                                                uint32_t x0, uint32_t x1,
                                                uint32_t& o0, uint32_t& o1) {
  uint32_t ks2 = k0 ^ k1 ^ 0x1BD11BDAu;
  x0 += k0; x1 += k1;
#define ROUND(r) { x0 += x1; x1 = (x1 << (r)) | (x1 >> (32 - (r))); x1 ^= x0; }
  ROUND(13) ROUND(15) ROUND(26) ROUND(6)
  x0 += k1; x1 += ks2 + 1u;
  ROUND(17) ROUND(29) ROUND(16) ROUND(24)
  x0 += ks2; x1 += k0 + 2u;
  ROUND(13) ROUND(15) ROUND(26) ROUND(6)
  x0 += k0; x1 += k1 + 3u;
  ROUND(17) ROUND(29) ROUND(16) ROUND(24)
  x0 += k1; x1 += ks2 + 4u;
  ROUND(13) ROUND(15) ROUND(26) ROUND(6)
  x0 += ks2; x1 += k0 + 5u;
#undef ROUND
  o0 = x0; o1 = x1;
}

__device__ __forceinline__ uint32_t rbits32(uint32_t k0, uint32_t k1, uint32_t i) {
  uint32_t a, b; tf2x32(k0, k1, 0u, i, a, b); return a ^ b;
}
__device__ __forceinline__ float uni01(uint32_t bits) {
  return __uint_as_float((bits >> 9) | 0x3f800000u) - 1.0f;
}

struct Keys { uint32_t k[NB][4][2]; };   // host-precomputed subkeys, by-value kernarg

// ---------------- kernel 1: per-anchor IoU sums (verbatim r15) + donecnt reset ----------------
__global__ __launch_bounds__(256) void k_iou(const float* __restrict__ tubes,
                                             const float* __restrict__ gtb,
                                             float* __restrict__ ov,
                                             int* __restrict__ donecnt) {
  int img = blockIdx.y;
  int a = blockIdx.z;
  int b = blockIdx.x;
  int tid = threadIdx.x;
  if (img == 0 && a == 0 && b == 0 && tid < NB) donecnt[tid] = 0;  // visible at kernel boundary
  int n = b * 256 + tid;
  bool valid = n < MM;
  int nn = valid ? n : MM - 1;
  bool isroi = nn < NROI;

  __shared__ float tub[256 * 7];
  __shared__ float4 g4[NA][T];
  __shared__ float gar[NA][T];
  {
    int rcnt = min(256, NROI - b * 256);       // 256, or 32 for b=78
    int f4cnt = (rcnt * 7) >> 2;
    const float4* src = (const float4*)(tubes + (size_t)img * NROI * 7 + (size_t)b * 256 * 7);
    float4* dst = (float4*)tub;
    for (int i = tid; i < f4cnt; i += 256) dst[i] = src[i];
  }
  for (int i = tid; i < NA * T; i += 256) {
    int aa = i / T, t = i - aa * T;
    const float* p = gtb + (((size_t)img * NA + aa) * T + t) * 5;
    float4 v = make_float4(p[0], p[1], p[2], p[3]);
    g4[aa][t] = v;
    gar[aa][t] = (v.z - v.x + 1.0f) * (v.w - v.y + 1.0f);
  }
  __syncthreads();

  float s = 0.0f;
  if (isroi) {
    const float* p = &tub[tid * 7];
    float rx1 = p[1], ry1 = p[2], rx2 = p[4], ry2 = p[5];
    int sf = (int)rintf(p[3]), ef = (int)rintf(p[6]);
    float rar = (rx2 - rx1 + 1.0f) * (ry2 - ry1 + 1.0f);
#pragma unroll
    for (int t = 0; t < T; ++t) {
      float4 gg = g4[a][t]; float ag = gar[a][t];
      float iw = fmaxf(fminf(rx2, gg.z) - fmaxf(rx1, gg.x) + 1.0f, 0.0f);
      float ih = fmaxf(fminf(ry2, gg.w) - fmaxf(ry1, gg.y) + 1.0f, 0.0f);
      float inter = iw * ih;
      float q = inter / (rar + ag - inter);
      s += ((t >= sf) && (t <= ef)) ? q : 0.0f;   // +0.0 keeps exact sum (verified r2-r15)
    }
  } else {
    int ga = nn - NROI;
#pragma unroll
    for (int t = 0; t < T; ++t) {
      float4 e = g4[ga][t]; float ar = gar[ga][t];
      float4 gg = g4[a][t]; float ag = gar[a][t];
      float iw = fmaxf(fminf(e.z, gg.z) - fmaxf(e.x, gg.x) + 1.0f, 0.0f);
      float ih = fmaxf(fminf(e.w, gg.w) - fmaxf(e.y, gg.y) + 1.0f, 0.0f);
      float inter = iw * ih;
      s += inter / (ar + ag - inter);
    }
  }
  if (valid) ov[((size_t)img * NA + a) * MMPAD + n] = s / 16.0f;
}

// ---------------- kernel 2: classify (all blocks) + last-block select+sample+outputs ----------------
__global__ __launch_bounds__(1024) void k_fused(const float* __restrict__ tubes,
                                                const float* __restrict__ gtb,
                                                const float* __restrict__ gta,
                                                const float* __restrict__ ov,
                                                unsigned char* __restrict__ asg,
                                                uint64_t* __restrict__ slots,
                                                int* __restrict__ cnts2,
                                                int* __restrict__ mins2,
                                                int* __restrict__ donecnt,
                                                Keys keys,
                                                float* __restrict__ out) {
  __shared__ uint64_t buf[LCAP];          // 128 KiB (select phase)
  __shared__ int hist[NBUCK];
  __shared__ int pref[NBUCK + 1];
  __shared__ int wsum[16];
  __shared__ int scnt[NBLK2], spref[NBLK2 + 1];
  __shared__ int wcnt[16][2], wmn[16][2];
  __shared__ int s_last;
  __shared__ int s_fgnum, s_bgnum, s_mnf, s_mnb, s_tot;
  __shared__ int s_keep[RPI];
  __shared__ int s_ak[RPI];
  __shared__ float s_lab[RPI];

  int img = blockIdx.y;
  int b = blockIdx.x;             // 0..19
  int tid = threadIdx.x;
  int lane = tid & 63;
  int w = tid >> 6;               // 16 waves

  // ======== phase A: classify + block compaction (verbatim r15 k_classify) ========
  {
    int n = b * 1024 + tid;
    bool valid = n < MM;
    int nn = valid ? n : MM - 1;
    const float* base_ov = ov + (size_t)img * NA * MMPAD + nn;
    float o0 = base_ov[0 * MMPAD];
    float o1 = base_ov[1 * MMPAD];
    float o2 = base_ov[2 * MMPAD];
    float o3 = base_ov[3 * MMPAD];
    float o4 = base_ov[4 * MMPAD];
    float best = o0; int barg = 0;
    if (o1 > best) { best = o1; barg = 1; }       // first-max == jnp.argmax
    if (o2 > best) { best = o2; barg = 2; }
    if (o3 > best) { best = o3; barg = 3; }
    if (o4 > best) { best = o4; barg = 4; }

    if (valid) asg[(size_t)img * MM + n] = (unsigned char)barg;

    bool isfg = valid && (best >= 0.5f);
    bool isbg = valid && (best < 0.5f) && (best >= 0.1f);

    unsigned long long mfg = __ballot(isfg);
    unsigned long long mbg = __ballot(isbg);
    unsigned long long mnf = __ballot(valid && !isfg);
    unsigned long long mnb = __ballot(valid && !isbg);
    int wavebase = b * 1024 + w * 64;
    if (lane == 0) {
      wcnt[w][0] = __popcll(mfg);
      wcnt[w][1] = __popcll(mbg);
      wmn[w][0] = mnf ? (wavebase + __ffsll(mnf) - 1) : 0x7FFFFFFF;
      wmn[w][1] = mnb ? (wavebase + __ffsll(mnb) - 1) : 0x7FFFFFFF;
    }
    __syncthreads();

    if (tid == 0) {
      int tf = 0, tb = 0, mf = 0x7FFFFFFF, mb = 0x7FFFFFFF;
#pragma unroll
      for (int w2 = 0; w2 < 16; ++w2) {
        tf += wcnt[w2][0]; tb += wcnt[w2][1];
        mf = min(mf, wmn[w2][0]); mb = min(mb, wmn[w2][1]);
      }
      int idx = img * NBLK2 + b;
      cnts2[idx]                = tf;
      cnts2[NB * NBLK2 + idx]   = tb;
      mins2[idx]                = mf;
      mins2[NB * NBLK2 + idx]   = mb;
    }

    int pf = 0, pb = 0;
    for (int w2 = 0; w2 < w; ++w2) { pf += wcnt[w2][0]; pb += wcnt[w2][1]; }
    unsigned long long below = (1ULL << lane) - 1ULL;
    uint64_t* slotF = slots + (size_t)(img * 2 + 0) * SORTCAP + b * 1024;
    uint64_t* slotB = slots + (size_t)(img * 2 + 1) * SORTCAP + b * 1024;
    if (isfg) {
      int pos = pf + __popcll(mfg & below);
      uint32_t m = rbits32(keys.k[img][0][0], keys.k[img][0][1], (uint32_t)n) >> 9;
      slotF[pos] = ((uint64_t)m << 32) | (uint32_t)n;
    }
    if (isbg) {
      int pos = pb + __popcll(mbg & below);
      uint32_t m = rbits32(keys.k[img][1][0], keys.k[img][1][1], (uint32_t)n) >> 9;
      slotB[pos] = ((uint64_t)m << 32) | (uint32_t)n;
    }
  }

  // ======== handoff: last classify block of this image proceeds to select ========
  __threadfence();                               // release our stores device-wide
  if (tid == 0) s_last = (atomicAdd(&donecnt[img], 1) == NBLK2 - 1) ? 1 : 0;
  __syncthreads();
  if (!s_last) return;
  __threadfence();                               // acquire: other blocks' stores now visible

  // totals for both lists (20+20 ints + mins)
  if (tid == 0) {
    int tf = 0, tb = 0, mf = 0x7FFFFFFF, mb = 0x7FFFFFFF;
#pragma unroll
    for (int bb = 0; bb < NBLK2; ++bb) {
      tf += cnts2[img * NBLK2 + bb];
      tb += cnts2[NB * NBLK2 + img * NBLK2 + bb];
      mf = min(mf, mins2[img * NBLK2 + bb]);
      mb = min(mb, mins2[NB * NBLK2 + img * NBLK2 + bb]);
    }
    s_fgnum = tf; s_bgnum = tb; s_mnf = mf; s_mnb = mb;
  }
  __syncthreads();
  int fg_num = s_fgnum, bg_num = s_bgnum;
  int min_nonfg = s_mnf, min_nonbg = s_mnb;
  int fg_this = (bg_num > 0) ? min(FGPI, fg_num) : (fg_num > 0 ? RPI : 0);

  float* o_rois = out;
  float* o_tub = out + (size_t)NB * RPI * 65;
  float* o_lab = o_tub + (size_t)NB * RPI * 7;
  float* o_tgt = o_lab + (size_t)NB * RPI;
  float* o_in  = o_tgt + (size_t)NB * RPI * 64;
  float* o_ou  = o_in  + (size_t)NB * RPI * 64;

  // ======== phase B: per-list bucket rank-select + keep (r14/r15-proven) ========
  for (int which = 0; which < 2; ++which) {
    uint64_t* arr = slots + (size_t)(img * 2 + which) * SORTCAP;
    int cnt = (which == 0) ? fg_num : bg_num;
    int min_non = (which == 0) ? min_nonfg : min_nonbg;
    bool ldsPath = (cnt <= LCAP);

    if (tid < NBLK2) scnt[tid] = cnts2[which * NB * NBLK2 + img * NBLK2 + tid];
    for (int i = tid; i < NBUCK; i += 1024) hist[i] = 0;
    __syncthreads();
    if (tid == 0) {
      int acc = 0;
#pragma unroll
      for (int bb = 0; bb < NBLK2; ++bb) { spref[bb] = acc; acc += scnt[bb]; }
      spref[NBLK2] = acc; s_tot = acc;
    }
    __syncthreads();

    if (cnt > 0 && ldsPath) {
      for (int s = tid; s < NBLK2 * 1024; s += 1024) {
        int bb = s >> 10, i = s & 1023;
        if (i < scnt[bb]) atomicAdd(&hist[(int)(arr[s] >> 44)], 1);
      }
      __syncthreads();
      {
        int a0 = hist[2 * tid], a1 = hist[2 * tid + 1];
        int ps = a0 + a1;
        int v = ps;
        for (int off = 1; off < 64; off <<= 1) {
          int u = __shfl_up(v, off);
          if (lane >= off) v += u;
        }
        if (lane == 63) wsum[w] = v;
        __syncthreads();
        if (tid == 0) {
          int acc = 0;
          for (int i = 0; i < 16; ++i) { int x = wsum[i]; wsum[i] = acc; acc += x; }
          pref[NBUCK] = acc;
        }
        __syncthreads();
        int excl = v - ps + wsum[w];
        pref[2 * tid] = excl;
        pref[2 * tid + 1] = excl + a0;
        hist[2 * tid] = excl;          // hist becomes scatter cursor
        hist[2 * tid + 1] = excl + a0;
      }
      __syncthreads();
      for (int s = tid; s < NBLK2 * 1024; s += 1024) {
        int bb = s >> 10, i = s & 1023;
        if (i < scnt[bb]) {
          uint64_t key = arr[s];
          int pos = atomicAdd(&hist[(int)(key >> 44)], 1);
          buf[pos] = key;
        }
      }
      __syncthreads();
    } else if (cnt > 1) {
      // global fallback: compaction + bitonic (cnt > 16384)
      for (int bb = 0; bb < NBLK2; ++bb) {
        uint64_t v = 0; int c = scnt[bb];
        if (tid < c) v = arr[bb * 1024 + tid];
        __syncthreads();
        if (tid < c) arr[spref[bb] + tid] = v;
        __syncthreads();
      }
      int n2 = 2; while (n2 < cnt) n2 <<= 1;
      for (int i = cnt + tid; i < n2; i += 1024) arr[i] = ~0ULL;
      __syncthreads();
      for (int k = 2; k <= n2; k <<= 1) {
        for (int j = k >> 1; j; j >>= 1) {
          for (int i = tid; i < n2; i += 1024) {
            int ixj = i ^ j;
            if (ixj > i) {
              uint64_t a = arr[i], bv = arr[ixj];
              bool up = (i & k) == 0;
              if (up ? (a > bv) : (a < bv)) { arr[i] = bv; arr[ixj] = a; }
            }
          }
          __syncthreads();
        }
      }
      __syncthreads();
    }

#define RANKQ(L, OUTV) {                                               \
    int l_ = (L);                                                      \
    if (ldsPath) {                                                     \
      int lo_ = 0, hi_ = NBUCK;                                        \
      while (hi_ - lo_ > 1) {                                          \
        int mid_ = (lo_ + hi_) >> 1;                                   \
        if (pref[mid_] <= l_) lo_ = mid_; else hi_ = mid_;             \
      }                                                                \
      int base_ = pref[lo_], cnt_ = pref[lo_ + 1] - base_;             \
      int ll_ = l_ - base_;                                            \
      uint64_t ans_ = 0;                                               \
      for (int i_ = 0; i_ < cnt_; ++i_) {                              \
        uint64_t ki_ = buf[base_ + i_];                                \
        int cl_ = 0;                                                   \
        for (int j_ = 0; j_ < cnt_; ++j_) cl_ += (buf[base_ + j_] < ki_); \
        if (cl_ == ll_) { ans_ = ki_; break; }                         \
      }                                                                \
      OUTV = (int)(uint32_t)(ans_ & 0xffffffffULL);                    \
    } else {                                                           \
      OUTV = (int)(uint32_t)(arr[l_] & 0xffffffffULL);                 \
    }                                                                  \
  }

    if (tid < RPI) {
      int r = tid;
      bool is_fg = r < fg_this;
      bool own = (is_fg == (which == 0));
      if (own) {
        int keep;
        if (which == 0) {
          if (bg_num > 0) {
            RANKQ(r, keep)                        // r < fg_this <= fg_num
          } else {
            float u3 = uni01(rbits32(keys.k[img][2][0], keys.k[img][2][1], (uint32_t)r));
            int q = (int)(u3 * (float)max(fg_num, 1));
            if (q >= fg_num) {
              if (fg_num >= MM) { RANKQ(MM - 1, keep) } else keep = min_non;
            } else {
              RANKQ(q, keep)
            }
          }
        } else {
          float u4 = uni01(rbits32(keys.k[img][3][0], keys.k[img][3][1], (uint32_t)r));
          int qb = (int)(u4 * (float)max(bg_num, 1));
          if (qb >= bg_num) {
            if (bg_num >= MM) { RANKQ(MM - 1, keep) } else keep = min_non;
          } else {
            RANKQ(qb, keep)
          }
        }

        int ak = asg[(size_t)img * MM + keep];
        float glab = gtb[(((size_t)img * NA + ak) * T + 0) * 5 + 4];
        float lab = is_fg ? glab : 0.0f;
        s_keep[r] = keep; s_ak[r] = ak; s_lab[r] = lab;

        size_t row = (size_t)img * RPI + r;
        float* pt = o_tub + row * 7;
        o_rois[row * 65] = (float)img;
        pt[0] = (float)img;
        if (keep < NROI) {
          const float* p = tubes + ((size_t)img * NROI + keep) * 7;
#pragma unroll
          for (int cc = 1; cc < 7; ++cc) pt[cc] = p[cc];
        } else {
          const float* p = gta + ((size_t)img * NA + (keep - NROI)) * 7;
#pragma unroll
          for (int cc = 1; cc < 7; ++cc) pt[cc] = p[cc - 1];
        }
        o_lab[row] = lab;
      }
    }
#undef RANKQ
    __syncthreads();
  }

  // ======== phase C: per-(row,frame) outputs for ALL 128 rows ========
  for (int i = tid; i < RPI * T; i += 1024) {
    int rl = i >> 4;
    int t = i & 15;
    size_t row = (size_t)img * RPI + rl;
    int keep = s_keep[rl];
    int ak = s_ak[rl];
    float lab = s_lab[rl];
    bool pos = lab > 0.0f;
    float posf = pos ? 1.0f : 0.0f;

    float ex1, ey1, ex2, ey2;
    if (keep < NROI) {
      const float* p = tubes + ((size_t)img * NROI + keep) * 7;
      int sf = (int)rintf(p[3]), ef = (int)rintf(p[6]);
      bool in = (t >= sf) && (t <= ef);
      ex1 = in ? p[1] : 0.0f; ey1 = in ? p[2] : 0.0f;
      ex2 = in ? p[4] : 0.0f; ey2 = in ? p[5] : 0.0f;
    } else {
      const float* p = gtb + (((size_t)img * NA + (keep - NROI)) * T + t) * 5;
      ex1 = p[0]; ey1 = p[1]; ex2 = p[2]; ey2 = p[3];
    }

    float* pr = o_rois + row * 65 + 1 + 4 * t;
    pr[0] = ex1; pr[1] = ey1; pr[2] = ex2; pr[3] = ey2;

    const float* gp = gtb + (((size_t)img * NA + ak) * T + t) * 5;
    float gx1 = gp[0], gy1 = gp[1], gx2 = gp[2], gy2 = gp[3];
    float ew = ex2 - ex1 + 1.0f, eh = ey2 - ey1 + 1.0f;
    float ecx = ex1 + 0.5f * ew, ecy = ey1 + 0.5f * eh;
    float gw = gx2 - gx1 + 1.0f, gh = gy2 - gy1 + 1.0f;
    float gcx = gx1 + 0.5f * gw, gcy = gy1 + 0.5f * gh;
    float t0 = ((gcx - ecx) / ew) / 0.1f;
    float t1 = ((gcy - ecy) / eh) / 0.1f;
    float t2 = logf(gw / ew) / 0.2f;
    float t3 = logf(gh / eh) / 0.2f;

    *(float4*)(o_tgt + row * 64 + 4 * t) =
        make_float4(pos ? t0 : 0.0f, pos ? t1 : 0.0f, pos ? t2 : 0.0f, pos ? t3 : 0.0f);
    float4 pf4 = make_float4(posf, posf, posf, posf);
    *(float4*)(o_in + row * 64 + 4 * t) = pf4;
    *(float4*)(o_ou + row * 64 + 4 * t) = pf4;
  }
}

extern "C" void kernel_launch(void* const* d_in, const int* in_sizes, int n_in,
                              void* d_out, int out_size, void* d_ws, size_t ws_size,
                              hipStream_t stream) {
  const float* tubes = (const float*)d_in[0];       // [8][20000][7]
  const float* gtb   = (const float*)d_in[1];       // [8][5][16][5]
  const float* gta   = (const float*)d_in[2];       // [8][5][7]
  float* out = (float*)d_out;
  char* ws = (char*)d_ws;

  // host-side key derivation (pure, deterministic): key(42)=(0,42); foldlike splits
  Keys keys;
  for (int img = 0; img < NB; ++img) {
    uint32_t r0, r1; tf2x32(0u, 42u, 0u, (uint32_t)img, r0, r1);
    for (int j = 0; j < 4; ++j) {
      uint32_t a, b; tf2x32(r0, r1, 0u, (uint32_t)j, a, b);
      keys.k[img][j][0] = a; keys.k[img][j][1] = b;
    }
  }

  // workspace layout (no init required anywhere; donecnt reset by k_iou each call)
  int* cnts2 = (int*)ws;                               // 1280
  int* mins2 = (int*)(ws + 1280);                      // 1280 -> ends 2560
  int* donecnt = (int*)(ws + 2560);                    // 32 B -> pad to 2688
  unsigned char* asg = (unsigned char*)(ws + 2688);    // 160040 -> ends 162728
  uint64_t* slots = (uint64_t*)(ws + 162728);          // 162728 % 8 == 0; 4,194,304 -> ends 4,357,032
  float* ov = (float*)(ws + 4357032);                  // 3,235,840 -> ends 7,592,872
  // total = 7,592,872 bytes

  dim3 gI(NBLK, NB, NA);
  k_iou<<<gI, 256, 0, stream>>>(tubes, gtb, ov, donecnt);
  dim3 gC(NBLK2, NB);
  k_fused<<<gC, 1024, 0, stream>>>(tubes, gtb, gta, ov, asg, slots, cnts2, mins2, donecnt, keys, out);
}

// Round 17
// 39.195 us; speedup vs baseline: 2.2728x; 2.2728x over previous
//
#include <hip/hip_runtime.h>
#include <stdint.h>

#define T 16
#define NB 8
#define NROI 20000
#define NA 5
#define MM (NROI + NA)   // 20005
#define MMPAD 20224      // per-(img,a) ov stride
#define RPI 128
#define FGPI 32
#define NBLK 79          // blocks per image in k_iou
#define NBLK2 20         // 1024-thread blocks per image in k_classify
#define SORTCAP 32768
#define LCAP 16384       // LDS bucket capacity (128 KiB)
#define NBUCK 2048

// ---------------- threefry2x32 (JAX-exact, 20 rounds), host+device ----------------
__host__ __device__ __forceinline__ void tf2x32(uint32_t k0, uint32_t k1,
                                                uint32_t x0, uint32_t x1,
                                                uint32_t& o0, uint32_t& o1) {
  uint32_t ks2 = k0 ^ k1 ^ 0x1BD11BDAu;
  x0 += k0; x1 += k1;
#define ROUND(r) { x0 += x1; x1 = (x1 << (r)) | (x1 >> (32 - (r))); x1 ^= x0; }
  ROUND(13) ROUND(15) ROUND(26) ROUND(6)
  x0 += k1; x1 += ks2 + 1u;
  ROUND(17) ROUND(29) ROUND(16) ROUND(24)
  x0 += ks2; x1 += k0 + 2u;
  ROUND(13) ROUND(15) ROUND(26) ROUND(6)
  x0 += k0; x1 += k1 + 3u;
  ROUND(17) ROUND(29) ROUND(16) ROUND(24)
  x0 += k1; x1 += ks2 + 4u;
  ROUND(13) ROUND(15) ROUND(26) ROUND(6)
  x0 += ks2; x1 += k0 + 5u;
#undef ROUND
  o0 = x0; o1 = x1;
}

__device__ __forceinline__ uint32_t rbits32(uint32_t k0, uint32_t k1, uint32_t i) {
  uint32_t a, b; tf2x32(k0, k1, 0u, i, a, b); return a ^ b;
}
__device__ __forceinline__ float uni01(uint32_t bits) {
  return __uint_as_float((bits >> 9) | 0x3f800000u) - 1.0f;
}

struct Keys { uint32_t k[NB][4][2]; };   // host-precomputed subkeys, by-value kernarg

// ---------------- kernel 1: per-anchor IoU sums (verbatim r9/r11, proven) ----------------
__global__ __launch_bounds__(256) void k_iou(const float* __restrict__ tubes,
                                             const float* __restrict__ gtb,
                                             float* __restrict__ ov) {
  int img = blockIdx.y;
  int a = blockIdx.z;
  int b = blockIdx.x;
  int tid = threadIdx.x;
  int n = b * 256 + tid;
  bool valid = n < MM;
  int nn = valid ? n : MM - 1;
  bool isroi = nn < NROI;

  __shared__ float tub[256 * 7];
  __shared__ float4 g4[NA][T];
  __shared__ float gar[NA][T];
  {
    int rcnt = min(256, NROI - b * 256);       // 256, or 32 for b=78
    int f4cnt = (rcnt * 7) >> 2;
    const float4* src = (const float4*)(tubes + (size_t)img * NROI * 7 + (size_t)b * 256 * 7);
    float4* dst = (float4*)tub;
    for (int i = tid; i < f4cnt; i += 256) dst[i] = src[i];
  }
  for (int i = tid; i < NA * T; i += 256) {
    int aa = i / T, t = i - aa * T;
    const float* p = gtb + (((size_t)img * NA + aa) * T + t) * 5;
    float4 v = make_float4(p[0], p[1], p[2], p[3]);
    g4[aa][t] = v;
    gar[aa][t] = (v.z - v.x + 1.0f) * (v.w - v.y + 1.0f);
  }
  __syncthreads();

  float s = 0.0f;
  if (isroi) {
    const float* p = &tub[tid * 7];
    float rx1 = p[1], ry1 = p[2], rx2 = p[4], ry2 = p[5];
    int sf = (int)rintf(p[3]), ef = (int)rintf(p[6]);
    float rar = (rx2 - rx1 + 1.0f) * (ry2 - ry1 + 1.0f);
#pragma unroll
    for (int t = 0; t < T; ++t) {
      float4 gg = g4[a][t]; float ag = gar[a][t];
      float iw = fmaxf(fminf(rx2, gg.z) - fmaxf(rx1, gg.x) + 1.0f, 0.0f);
      float ih = fmaxf(fminf(ry2, gg.w) - fmaxf(ry1, gg.y) + 1.0f, 0.0f);
      float inter = iw * ih;
      float q = inter / (rar + ag - inter);
      s += ((t >= sf) && (t <= ef)) ? q : 0.0f;   // +0.0 keeps exact sum (verified r2-r15)
    }
  } else {
    int ga = nn - NROI;
#pragma unroll
    for (int t = 0; t < T; ++t) {
      float4 e = g4[ga][t]; float ar = gar[ga][t];
      float4 gg = g4[a][t]; float ag = gar[a][t];
      float iw = fmaxf(fminf(e.z, gg.z) - fmaxf(e.x, gg.x) + 1.0f, 0.0f);
      float ih = fmaxf(fminf(e.w, gg.w) - fmaxf(e.y, gg.y) + 1.0f, 0.0f);
      float inter = iw * ih;
      s += inter / (ar + ag - inter);
    }
  }
  if (valid) ov[((size_t)img * NA + a) * MMPAD + n] = s / 16.0f;
}

// ---------------- kernel 2: argmax + classify + compaction (verbatim r11, proven) ----------------
__global__ __launch_bounds__(1024) void k_classify(const float* __restrict__ ov,
                                                   unsigned char* __restrict__ asg,
                                                   uint64_t* __restrict__ slots,
                                                   int* __restrict__ cnts2,
                                                   int* __restrict__ mins2,
                                                   Keys keys) {
  int img = blockIdx.y;
  int b = blockIdx.x;             // 0..19
  int tid = threadIdx.x;
  int n = b * 1024 + tid;
  bool valid = n < MM;
  int nn = valid ? n : MM - 1;
  int lane = tid & 63;
  int w = tid >> 6;               // 16 waves

  const float* base_ov = ov + (size_t)img * NA * MMPAD + nn;
  float o0 = base_ov[0 * MMPAD];
  float o1 = base_ov[1 * MMPAD];
  float o2 = base_ov[2 * MMPAD];
  float o3 = base_ov[3 * MMPAD];
  float o4 = base_ov[4 * MMPAD];
  float best = o0; int barg = 0;
  if (o1 > best) { best = o1; barg = 1; }       // first-max == jnp.argmax
  if (o2 > best) { best = o2; barg = 2; }
  if (o3 > best) { best = o3; barg = 3; }
  if (o4 > best) { best = o4; barg = 4; }

  if (valid) asg[(size_t)img * MM + n] = (unsigned char)barg;

  bool isfg = valid && (best >= 0.5f);
  bool isbg = valid && (best < 0.5f) && (best >= 0.1f);

  __shared__ int wcnt[16][2];
  __shared__ int wmn[16][2];
  unsigned long long mfg = __ballot(isfg);
  unsigned long long mbg = __ballot(isbg);
  unsigned long long mnf = __ballot(valid && !isfg);
  unsigned long long mnb = __ballot(valid && !isbg);
  int wavebase = b * 1024 + w * 64;
  if (lane == 0) {
    wcnt[w][0] = __popcll(mfg);
    wcnt[w][1] = __popcll(mbg);
    wmn[w][0] = mnf ? (wavebase + __ffsll(mnf) - 1) : 0x7FFFFFFF;
    wmn[w][1] = mnb ? (wavebase + __ffsll(mnb) - 1) : 0x7FFFFFFF;
  }
  __syncthreads();

  if (tid == 0) {
    int tf = 0, tb = 0, mf = 0x7FFFFFFF, mb = 0x7FFFFFFF;
#pragma unroll
    for (int w2 = 0; w2 < 16; ++w2) {
      tf += wcnt[w2][0]; tb += wcnt[w2][1];
      mf = min(mf, wmn[w2][0]); mb = min(mb, wmn[w2][1]);
    }
    int idx = img * NBLK2 + b;
    cnts2[idx]                = tf;
    cnts2[NB * NBLK2 + idx]   = tb;
    mins2[idx]                = mf;
    mins2[NB * NBLK2 + idx]   = mb;
  }

  int pf = 0, pb = 0;
  for (int w2 = 0; w2 < w; ++w2) { pf += wcnt[w2][0]; pb += wcnt[w2][1]; }
  unsigned long long below = (1ULL << lane) - 1ULL;
  uint64_t* slotF = slots + (size_t)(img * 2 + 0) * SORTCAP + b * 1024;
  uint64_t* slotB = slots + (size_t)(img * 2 + 1) * SORTCAP + b * 1024;
  if (isfg) {
    int pos = pf + __popcll(mfg & below);
    uint32_t m = rbits32(keys.k[img][0][0], keys.k[img][0][1], (uint32_t)n) >> 9;
    slotF[pos] = ((uint64_t)m << 32) | (uint32_t)n;
  }
  if (isbg) {
    int pos = pb + __popcll(mbg & below);
    uint32_t m = rbits32(keys.k[img][1][0], keys.k[img][1][1], (uint32_t)n) >> 9;
    slotB[pos] = ((uint64_t)m << 32) | (uint32_t)n;
  }
}

// ---------------- kernel 3: bucket rank-select + sample + outputs (verbatim r14, ak from asg) ----------------
__global__ __launch_bounds__(1024) void k_sortsample(const float* __restrict__ tubes,
                                                     const float* __restrict__ gtb,
                                                     const float* __restrict__ gta,
                                                     const unsigned char* __restrict__ asg,
                                                     uint64_t* __restrict__ slots,
                                                     const int* __restrict__ cnts2,
                                                     const int* __restrict__ mins2,
                                                     Keys keys,
                                                     float* __restrict__ out) {
  __shared__ uint64_t buf[LCAP];          // 128 KiB, bucket-ordered keys
  __shared__ int hist[NBUCK];             // histogram, then reused as scatter cursors
  __shared__ int pref[NBUCK + 1];
  __shared__ int wsum[16];
  __shared__ int scnt[NBLK2], spref[NBLK2 + 1];
  __shared__ int s_tot, s_oth, s_mn;
  __shared__ int s_keep[RPI];
  __shared__ int s_ak[RPI];
  __shared__ float s_lab[RPI];
  __shared__ unsigned char s_own[RPI];

  int list = blockIdx.x;           // (img<<1)|which
  int img = list >> 1;
  int which = list & 1;
  int tid = threadIdx.x;
  int lane = tid & 63, wv = tid >> 6;
  uint64_t* arr = slots + (size_t)(img * 2 + which) * SORTCAP;
  const int* cn = cnts2 + which * NB * NBLK2 + img * NBLK2;
  const int* co = cnts2 + (1 - which) * NB * NBLK2 + img * NBLK2;
  const int* mn = mins2 + which * NB * NBLK2 + img * NBLK2;

  if (tid < NBLK2) scnt[tid] = cn[tid];
  for (int i = tid; i < NBUCK; i += 1024) hist[i] = 0;
  __syncthreads();
  if (tid == 0) {
    int acc = 0, mmn = 0x7FFFFFFF, oth = 0;
#pragma unroll
    for (int bb = 0; bb < NBLK2; ++bb) {
      spref[bb] = acc; acc += scnt[bb];
      mmn = min(mmn, mn[bb]); oth += co[bb];
    }
    spref[NBLK2] = acc; s_tot = acc; s_mn = mmn; s_oth = oth;
  }
  __syncthreads();
  int cnt = s_tot, min_non = s_mn;
  int fg_num = (which == 0) ? cnt : s_oth;
  int bg_num = (which == 0) ? s_oth : cnt;
  bool ldsPath = (cnt <= LCAP);

  if (cnt > 0 && ldsPath) {
    // ---- pass 1: histogram (bucket = top 11 bits of 23-bit mantissa key) ----
    for (int s = tid; s < NBLK2 * 1024; s += 1024) {
      int bb = s >> 10, i = s & 1023;
      if (i < scnt[bb]) {
        uint64_t key = arr[s];
        atomicAdd(&hist[(int)(key >> 44)], 1);
      }
    }
    __syncthreads();
    // ---- prefix sum over 2048 buckets (r12-proven wave scan) ----
    {
      int a0 = hist[2 * tid], a1 = hist[2 * tid + 1];
      int ps = a0 + a1;
      int v = ps;
      for (int off = 1; off < 64; off <<= 1) {
        int u = __shfl_up(v, off);
        if (lane >= off) v += u;
      }
      if (lane == 63) wsum[wv] = v;
      __syncthreads();
      if (tid == 0) {
        int acc = 0;
        for (int i = 0; i < 16; ++i) { int x = wsum[i]; wsum[i] = acc; acc += x; }
        pref[NBUCK] = acc;
      }
      __syncthreads();
      int excl = v - ps + wsum[wv];
      pref[2 * tid] = excl;
      pref[2 * tid + 1] = excl + a0;
      hist[2 * tid] = excl;          // hist becomes scatter cursor
      hist[2 * tid + 1] = excl + a0;
    }
    __syncthreads();
    // ---- pass 2: scatter into bucket order (within-bucket order arbitrary) ----
    for (int s = tid; s < NBLK2 * 1024; s += 1024) {
      int bb = s >> 10, i = s & 1023;
      if (i < scnt[bb]) {
        uint64_t key = arr[s];
        int pos = atomicAdd(&hist[(int)(key >> 44)], 1);
        buf[pos] = key;
      }
    }
    __syncthreads();
  } else if (cnt > 1) {
    // ---- global fallback: compaction + bitonic (cnt > 16384) ----
    for (int bb = 0; bb < NBLK2; ++bb) {
      uint64_t v = 0; int c = scnt[bb];
      if (tid < c) v = arr[bb * 1024 + tid];
      __syncthreads();
      if (tid < c) arr[spref[bb] + tid] = v;
      __syncthreads();
    }
    int n2 = 2; while (n2 < cnt) n2 <<= 1;
    for (int i = cnt + tid; i < n2; i += 1024) arr[i] = ~0ULL;
    __syncthreads();
    for (int k = 2; k <= n2; k <<= 1) {
      for (int j = k >> 1; j; j >>= 1) {
        for (int i = tid; i < n2; i += 1024) {
          int ixj = i ^ j;
          if (ixj > i) {
            uint64_t a = arr[i], bv = arr[ixj];
            bool up = (i & k) == 0;
            if (up ? (a > bv) : (a < bv)) { arr[i] = bv; arr[ixj] = a; }
          }
        }
        __syncthreads();
      }
    }
    __syncthreads();
  }

  // ---- sampling for owned rows ----
  float* o_rois = out;
  float* o_tub = out + (size_t)NB * RPI * 65;
  float* o_lab = o_tub + (size_t)NB * RPI * 7;
  float* o_tgt = o_lab + (size_t)NB * RPI;
  float* o_in  = o_tgt + (size_t)NB * RPI * 64;
  float* o_ou  = o_in  + (size_t)NB * RPI * 64;

  int fg_this = (bg_num > 0) ? min(FGPI, fg_num) : (fg_num > 0 ? RPI : 0);

  // rank l -> roi index: LDS bucket rank-select (r14-proven) or sorted-global direct
#define RANKQ(L, OUTV) {                                               \
    int l_ = (L);                                                      \
    if (ldsPath) {                                                     \
      int lo_ = 0, hi_ = NBUCK;                                        \
      while (hi_ - lo_ > 1) {                                          \
        int mid_ = (lo_ + hi_) >> 1;                                   \
        if (pref[mid_] <= l_) lo_ = mid_; else hi_ = mid_;             \
      }                                                                \
      int base_ = pref[lo_], cnt_ = pref[lo_ + 1] - base_;             \
      int ll_ = l_ - base_;                                            \
      uint64_t ans_ = 0;                                               \
      for (int i_ = 0; i_ < cnt_; ++i_) {                              \
        uint64_t ki_ = buf[base_ + i_];                                \
        int cl_ = 0;                                                   \
        for (int j_ = 0; j_ < cnt_; ++j_) cl_ += (buf[base_ + j_] < ki_); \
        if (cl_ == ll_) { ans_ = ki_; break; }                         \
      }                                                                \
      OUTV = (int)(uint32_t)(ans_ & 0xffffffffULL);                    \
    } else {                                                           \
      OUTV = (int)(uint32_t)(arr[l_] & 0xffffffffULL);                 \
    }                                                                  \
  }

  if (tid < RPI) {
    int r = tid;
    bool is_fg = r < fg_this;
    bool own = (is_fg == (which == 0));
    s_own[r] = own ? 1 : 0;
    if (own) {
      int keep;
      if (which == 0) {
        if (bg_num > 0) {
          RANKQ(r, keep)                          // r < fg_this <= fg_num
        } else {
          float u3 = uni01(rbits32(keys.k[img][2][0], keys.k[img][2][1], (uint32_t)r));
          int q = (int)(u3 * (float)max(fg_num, 1));
          if (q >= fg_num) {
            if (fg_num >= MM) { RANKQ(MM - 1, keep) } else keep = min_non;
          } else {
            RANKQ(q, keep)
          }
        }
      } else {
        float u4 = uni01(rbits32(keys.k[img][3][0], keys.k[img][3][1], (uint32_t)r));
        int qb = (int)(u4 * (float)max(bg_num, 1));
        if (qb >= bg_num) {
          if (bg_num >= MM) { RANKQ(MM - 1, keep) } else keep = min_non;
        } else {
          RANKQ(qb, keep)
        }
      }

      int ak = asg[(size_t)img * MM + keep];
      float glab = gtb[(((size_t)img * NA + ak) * T + 0) * 5 + 4];
      float lab = is_fg ? glab : 0.0f;
      s_keep[r] = keep; s_ak[r] = ak; s_lab[r] = lab;

      size_t row = (size_t)img * RPI + r;
      float* pt = o_tub + row * 7;
      o_rois[row * 65] = (float)img;
      pt[0] = (float)img;
      if (keep < NROI) {
        const float* p = tubes + ((size_t)img * NROI + keep) * 7;
#pragma unroll
        for (int cc = 1; cc < 7; ++cc) pt[cc] = p[cc];
      } else {
        const float* p = gta + ((size_t)img * NA + (keep - NROI)) * 7;
#pragma unroll
        for (int cc = 1; cc < 7; ++cc) pt[cc] = p[cc - 1];
      }
      o_lab[row] = lab;
    }
  }
#undef RANKQ
  __syncthreads();

  // ---- per-(row,frame) outputs for owned rows ----
  for (int i = tid; i < RPI * T; i += 1024) {
    int rl = i >> 4;
    if (!s_own[rl]) continue;
    int t = i & 15;
    size_t row = (size_t)img * RPI + rl;
    int keep = s_keep[rl];
    int ak = s_ak[rl];
    float lab = s_lab[rl];
    bool pos = lab > 0.0f;
    float posf = pos ? 1.0f : 0.0f;

    float ex1, ey1, ex2, ey2;
    if (keep < NROI) {
      const float* p = tubes + ((size_t)img * NROI + keep) * 7;
      int sf = (int)rintf(p[3]), ef = (int)rintf(p[6]);
      bool in = (t >= sf) && (t <= ef);
      ex1 = in ? p[1] : 0.0f; ey1 = in ? p[2] : 0.0f;
      ex2 = in ? p[4] : 0.0f; ey2 = in ? p[5] : 0.0f;
    } else {
      const float* p = gtb + (((size_t)img * NA + (keep - NROI)) * T + t) * 5;
      ex1 = p[0]; ey1 = p[1]; ex2 = p[2]; ey2 = p[3];
    }

    float* pr = o_rois + row * 65 + 1 + 4 * t;
    pr[0] = ex1; pr[1] = ey1; pr[2] = ex2; pr[3] = ey2;

    const float* gp = gtb + (((size_t)img * NA + ak) * T + t) * 5;
    float gx1 = gp[0], gy1 = gp[1], gx2 = gp[2], gy2 = gp[3];
    float ew = ex2 - ex1 + 1.0f, eh = ey2 - ey1 + 1.0f;
    float ecx = ex1 + 0.5f * ew, ecy = ey1 + 0.5f * eh;
    float gw = gx2 - gx1 + 1.0f, gh = gy2 - gy1 + 1.0f;
    float gcx = gx1 + 0.5f * gw, gcy = gy1 + 0.5f * gh;
    float t0 = ((gcx - ecx) / ew) / 0.1f;
    float t1 = ((gcy - ecy) / eh) / 0.1f;
    float t2 = logf(gw / ew) / 0.2f;
    float t3 = logf(gh / eh) / 0.2f;

    *(float4*)(o_tgt + row * 64 + 4 * t) =
        make_float4(pos ? t0 : 0.0f, pos ? t1 : 0.0f, pos ? t2 : 0.0f, pos ? t3 : 0.0f);
    float4 pf4 = make_float4(posf, posf, posf, posf);
    *(float4*)(o_in + row * 64 + 4 * t) = pf4;
    *(float4*)(o_ou + row * 64 + 4 * t) = pf4;
  }
}

extern "C" void kernel_launch(void* const* d_in, const int* in_sizes, int n_in,
                              void* d_out, int out_size, void* d_ws, size_t ws_size,
                              hipStream_t stream) {
  const float* tubes = (const float*)d_in[0];       // [8][20000][7]
  const float* gtb   = (const float*)d_in[1];       // [8][5][16][5]
  const float* gta   = (const float*)d_in[2];       // [8][5][7]
  float* out = (float*)d_out;
  char* ws = (char*)d_ws;

  // host-side key derivation (pure, deterministic): key(42)=(0,42); foldlike splits
  Keys keys;
  for (int img = 0; img < NB; ++img) {
    uint32_t r0, r1; tf2x32(0u, 42u, 0u, (uint32_t)img, r0, r1);
    for (int j = 0; j < 4; ++j) {
      uint32_t a, b; tf2x32(r0, r1, 0u, (uint32_t)j, a, b);
      keys.k[img][j][0] = a; keys.k[img][j][1] = b;
    }
  }

  // workspace layout (no init required anywhere)
  int* cnts2 = (int*)ws;                               // 1280
  int* mins2 = (int*)(ws + 1280);                      // 1280 -> ends 2560
  unsigned char* asg = (unsigned char*)(ws + 2560);    // 160040 -> ends 162600
  uint64_t* slots = (uint64_t*)(ws + 162600);          // 162600 % 8 == 0; 4,194,304 -> ends 4,356,904
  float* ov = (float*)(ws + 4356904);                  // 3,235,840 -> ends 7,592,744
  // total = 7,592,744 bytes

  dim3 gI(NBLK, NB, NA);
  k_iou<<<gI, 256, 0, stream>>>(tubes, gtb, ov);
  dim3 gC(NBLK2, NB);
  k_classify<<<gC, 1024, 0, stream>>>(ov, asg, slots, cnts2, mins2, keys);
  k_sortsample<<<16, 1024, 0, stream>>>(tubes, gtb, gta, asg, slots, cnts2, mins2, keys, out);
}